// Round 2
// baseline (150.508 us; speedup 1.0000x reference)
//
#include <hip/hip_runtime.h>

// RoI max-pooling. features [4,256,38,38] f32, rois [512,5] f32,
// out [512,256,7,7] f32.
//
// Decomposition: grid = (7, 512). blockIdx.y = ROI index -> ROI decode is
// wave-uniform (scalar loads / SALU). Thread t in [0,1792) -> c = t/7,
// p = t%7; each thread computes the 7 q-outputs of its (c,p) row of bins,
// so the x-segment loop bounds are SGPR-uniform (no lane divergence in x).

#define NROIS 512
#define CCH   256
#define FH    38
#define FW    38
#define PH    7
#define PW    7
#define SCALE 0.0625f

__global__ __launch_bounds__(256) void roipool_kernel(
    const float* __restrict__ feat,
    const float* __restrict__ rois,
    float* __restrict__ out)
{
    const int n = blockIdx.y;
    const int t = blockIdx.x * 256 + threadIdx.x;   // 0..1791
    const int c = t / 7;
    const int p = t - c * 7;

    // ROI decode — uniform across the block (depends only on blockIdx.y).
    const float* r = rois + n * 5;
    const int b = (int)r[0];
    int x1 = (int)(r[1] * SCALE);   // coords >= 0, cast == trunc
    int y1 = (int)(r[2] * SCALE);
    int x2 = (int)(r[3] * SCALE);
    int y2 = (int)(r[4] * SCALE);
    x1 = min(max(x1, 0), FW - 1);
    y1 = min(max(y1, 0), FH - 1);
    x2 = min(max(x2, 0), FW - 1);
    y2 = min(max(y2, 0), FH - 1);
    const int hh = y2 - y1 + 1;   // >= 1
    const int ww = x2 - x1 + 1;   // >= 1

    // y-bin for this thread's p (lane-varying by <=1 iteration).
    const int ys = y1 + (p * hh) / PH;
    const int ye = y1 + ((p + 1) * hh + PH - 1) / PH;   // ceil

    // x-bins for all 7 q — uniform (SGPR) across the wave.
    const int xs0 = x1 + (0 * ww) / PW, xe0 = x1 + (1 * ww + PW - 1) / PW;
    const int xs1 = x1 + (1 * ww) / PW, xe1 = x1 + (2 * ww + PW - 1) / PW;
    const int xs2 = x1 + (2 * ww) / PW, xe2 = x1 + (3 * ww + PW - 1) / PW;
    const int xs3 = x1 + (3 * ww) / PW, xe3 = x1 + (4 * ww + PW - 1) / PW;
    const int xs4 = x1 + (4 * ww) / PW, xe4 = x1 + (5 * ww + PW - 1) / PW;
    const int xs5 = x1 + (5 * ww) / PW, xe5 = x1 + (6 * ww + PW - 1) / PW;
    const int xs6 = x1 + (6 * ww) / PW, xe6 = x1 + (7 * ww + PW - 1) / PW;

    const float* base = feat + ((size_t)b * CCH + c) * (FH * FW);

    const float NEG = -3.402823466e+38f;
    float a0 = NEG, a1 = NEG, a2 = NEG, a3 = NEG, a4 = NEG, a5 = NEG, a6 = NEG;

    for (int y = ys; y < ye; ++y) {
        const float* row = base + y * FW;
        for (int x = xs0; x < xe0; ++x) a0 = fmaxf(a0, row[x]);
        for (int x = xs1; x < xe1; ++x) a1 = fmaxf(a1, row[x]);
        for (int x = xs2; x < xe2; ++x) a2 = fmaxf(a2, row[x]);
        for (int x = xs3; x < xe3; ++x) a3 = fmaxf(a3, row[x]);
        for (int x = xs4; x < xe4; ++x) a4 = fmaxf(a4, row[x]);
        for (int x = xs5; x < xe5; ++x) a5 = fmaxf(a5, row[x]);
        for (int x = xs6; x < xe6; ++x) a6 = fmaxf(a6, row[x]);
    }

    // out offset: ((n*CCH + c)*PH + p)*PW == n*12544 + 7*t
    float* o = out + (size_t)n * (CCH * PH * PW) + 7 * (size_t)t;
    o[0] = a0; o[1] = a1; o[2] = a2; o[3] = a3; o[4] = a4; o[5] = a5; o[6] = a6;
}

extern "C" void kernel_launch(void* const* d_in, const int* in_sizes, int n_in,
                              void* d_out, int out_size, void* d_ws, size_t ws_size,
                              hipStream_t stream) {
    const float* feat = (const float*)d_in[0];
    const float* rois = (const float*)d_in[1];
    float* out = (float*)d_out;

    dim3 grid(7, NROIS);   // 7 blocks x 256 threads = 1792 = 256 ch * 7 p per ROI
    roipool_kernel<<<grid, 256, 0, stream>>>(feat, rois, out);
}

// Round 3
// 83.376 us; speedup vs baseline: 1.8052x; 1.8052x over previous
//
#include <hip/hip_runtime.h>

// RoI max-pool, separable (rows then cols), wave-cooperative.
// features [4,256,38,38] f32, rois [512,5] f32, out [512,256,7,7] f32.
//
// grid = (32, 512): blockIdx.y = ROI n (=> scalar ROI decode),
// blockIdx.x = channel octet. Block 256 = 4 waves; wave handles 2 channels.
// Phase 1: lane = (c2 = lane>>5, x = lane&31 within ROI cols); loop y over
//          ROI rows (wave-uniform bounds), one coalesced load per y,
//          7 row-max accumulators with uniform bin tests. Row-maxes -> LDS.
// Phase 2: lane = output (c2, p, q); 7 clamped LDS reads (max bin width <= 7),
//          fully unrolled; duplicates harmless under max.

#define NROIS 512
#define CCH   256
#define FH    38
#define FW    38
#define SCALE 0.0625f
#define NEGF  (-3.402823466e+38f)

__global__ __launch_bounds__(256) void roipool_kernel(
    const float* __restrict__ feat,
    const float* __restrict__ rois,
    float* __restrict__ out)
{
    __shared__ float ry[4][2][7][40];   // [wave][c2][p][x-index], padded width

    const int n    = blockIdx.y;
    const int wave = threadIdx.x >> 6;
    const int lane = threadIdx.x & 63;

    // ---- uniform ROI decode (scalar) ----
    const float* r = rois + n * 5;
    const int b = (int)r[0];
    int x1 = (int)(r[1] * SCALE);
    int y1 = (int)(r[2] * SCALE);
    int x2 = (int)(r[3] * SCALE);
    int y2 = (int)(r[4] * SCALE);
    x1 = min(max(x1, 0), FW - 1);
    y1 = min(max(y1, 0), FH - 1);
    x2 = min(max(x2, 0), FW - 1);
    y2 = min(max(y2, 0), FH - 1);
    const int hh = y2 - y1 + 1;   // 1..38
    const int ww = x2 - x1 + 1;   // 1..38

    // y-bin boundaries (uniform scalars)
    const int s0 = y1 + (0 * hh) / 7, e0 = y1 + (1 * hh + 6) / 7;
    const int s1 = y1 + (1 * hh) / 7, e1 = y1 + (2 * hh + 6) / 7;
    const int s2 = y1 + (2 * hh) / 7, e2 = y1 + (3 * hh + 6) / 7;
    const int s3 = y1 + (3 * hh) / 7, e3 = y1 + (4 * hh + 6) / 7;
    const int s4 = y1 + (4 * hh) / 7, e4 = y1 + (5 * hh + 6) / 7;
    const int s5 = y1 + (5 * hh) / 7, e5 = y1 + (6 * hh + 6) / 7;
    const int s6 = y1 + (6 * hh) / 7, e6 = y1 + (7 * hh + 6) / 7;

    const int c0 = (blockIdx.x * 4 + wave) * 2;   // first channel of this wave
    const int cL = lane >> 5;                     // 0/1
    const int xl = lane & 31;

    const float* plane = feat + ((size_t)(b * CCH + c0 + cL)) * (FH * FW);

    // ---- phase 1: row pooling, column-per-lane ----
    for (int xc = 0; xc < ww; xc += 32) {         // >1 chunk only if ww > 32
        const int x     = x1 + xc + xl;
        const int xload = min(x, x2);             // clamp: duplicates harmless

        float a0 = NEGF, a1 = NEGF, a2 = NEGF, a3 = NEGF,
              a4 = NEGF, a5 = NEGF, a6 = NEGF;

        for (int y = y1; y <= y2; ++y) {          // wave-uniform trip count
            const float v = plane[y * FW + xload];
            if (y >= s0 && y < e0) a0 = fmaxf(a0, v);
            if (y >= s1 && y < e1) a1 = fmaxf(a1, v);
            if (y >= s2 && y < e2) a2 = fmaxf(a2, v);
            if (y >= s3 && y < e3) a3 = fmaxf(a3, v);
            if (y >= s4 && y < e4) a4 = fmaxf(a4, v);
            if (y >= s5 && y < e5) a5 = fmaxf(a5, v);
            if (y >= s6 && y < e6) a6 = fmaxf(a6, v);
        }

        if (x <= x2) {
            const int xi = xc + xl;               // 0..ww-1 < 40
            ry[wave][cL][0][xi] = a0;
            ry[wave][cL][1][xi] = a1;
            ry[wave][cL][2][xi] = a2;
            ry[wave][cL][3][xi] = a3;
            ry[wave][cL][4][xi] = a4;
            ry[wave][cL][5][xi] = a5;
            ry[wave][cL][6][xi] = a6;
        }
    }

    __syncthreads();

    // ---- phase 2: column pooling from LDS, one output per lane-slot ----
    const int base_out = (n * CCH + c0) * 49;     // + cc*49 + p*7 + q
    #pragma unroll
    for (int i = 0; i < 2; ++i) {
        const int oid = i * 64 + lane;            // 0..97 valid
        if (oid < 98) {
            const int cc = (oid >= 49) ? 1 : 0;
            const int pq = oid - 49 * cc;
            const int p  = pq / 7;                // compile-time magic div
            const int q  = pq - p * 7;

            const int xs = (q * ww) / 7;          // relative to x1
            const int xe = ((q + 1) * ww + 6) / 7;
            const int xm = xe - 1;                // nx <= 7 always

            float m = NEGF;
            #pragma unroll
            for (int j = 0; j < 7; ++j) {
                const int xi = min(xs + j, xm);   // clamped duplicates ok
                m = fmaxf(m, ry[wave][cc][p][xi]);
            }
            out[base_out + oid] = m;
        }
    }
}

extern "C" void kernel_launch(void* const* d_in, const int* in_sizes, int n_in,
                              void* d_out, int out_size, void* d_ws, size_t ws_size,
                              hipStream_t stream) {
    const float* feat = (const float*)d_in[0];
    const float* rois = (const float*)d_in[1];
    float* out = (float*)d_out;

    dim3 grid(32, NROIS);   // 32 * (4 waves * 2 ch) = 256 channels
    roipool_kernel<<<grid, 256, 0, stream>>>(feat, rois, out);
}

// Round 4
// 60.703 us; speedup vs baseline: 2.4794x; 1.3735x over previous
//
#include <hip/hip_runtime.h>

// RoI max-pool via channel-last transpose.
// features [4,256,38,38] f32, rois [512,5] f32, out [512,256,7,7] f32.
//
// Kernel 1: transpose features -> featT [4][38*38][256] in d_ws.
// Kernel 2: block = (ROI n, 64-channel group). Lane = channel. Per bin,
//           loop cells with wave-uniform bounds; each cell = one coalesced
//           256B load + fmax. Stage [49][ch] in LDS, write out coalesced.

#define NROIS 512
#define CCH   256
#define FH    38
#define FW    38
#define HW    (FH * FW)          // 1444
#define SCALE 0.0625f
#define NEGF  (-3.402823466e+38f)

// ---------------- Kernel 1: tiled transpose ----------------
// src [4][256][1444] -> dst [4][1444][256]
__global__ __launch_bounds__(256) void transpose_kernel(
    const float* __restrict__ src, float* __restrict__ dst)
{
    __shared__ float tile[32][33];
    const int b  = blockIdx.z;
    const int c0 = blockIdx.y * 32;       // channel tile
    const int s0 = blockIdx.x * 32;       // yx tile
    const int tx = threadIdx.x;           // 0..31
    const int ty = threadIdx.y;           // 0..7

    #pragma unroll
    for (int k = 0; k < 4; ++k) {
        const int c = c0 + ty + k * 8;    // < 256 always
        const int s = s0 + tx;
        if (s < HW)
            tile[ty + k * 8][tx] = src[((size_t)b * CCH + c) * HW + s];
    }
    __syncthreads();
    #pragma unroll
    for (int k = 0; k < 4; ++k) {
        const int s = s0 + ty + k * 8;
        const int c = c0 + tx;
        if (s < HW)
            dst[((size_t)b * HW + s) * CCH + c] = tile[tx][ty + k * 8];
    }
}

// ---------------- Kernel 2: pooling ----------------
__global__ __launch_bounds__(256) void roipool_kernel(
    const float* __restrict__ featT,
    const float* __restrict__ rois,
    float* __restrict__ out)
{
    __shared__ float smem[49][65];        // [pq][channel-in-group], padded
    __shared__ int ysA[7], yeA[7], xsA[7], xeA[7];

    const int n    = blockIdx.y;
    const int cg   = blockIdx.x * 64;     // channel group base
    const int tid  = threadIdx.x;
    const int wave = tid >> 6;
    const int lane = tid & 63;

    // ROI decode (uniform per block)
    const float* r = rois + n * 5;
    const int b = (int)r[0];
    int x1 = (int)(r[1] * SCALE);
    int y1 = (int)(r[2] * SCALE);
    int x2 = (int)(r[3] * SCALE);
    int y2 = (int)(r[4] * SCALE);
    x1 = min(max(x1, 0), FW - 1);
    y1 = min(max(y1, 0), FH - 1);
    x2 = min(max(x2, 0), FW - 1);
    y2 = min(max(y2, 0), FH - 1);
    const int hh = y2 - y1 + 1;
    const int ww = x2 - x1 + 1;

    if (tid < 7) {
        ysA[tid] = y1 + (tid * hh) / 7;
        yeA[tid] = y1 + ((tid + 1) * hh + 6) / 7;
        xsA[tid] = x1 + (tid * ww) / 7;
        xeA[tid] = x1 + ((tid + 1) * ww + 6) / 7;
    }
    __syncthreads();

    // phase 1: each wave handles bins pq = wave, wave+4, ...
    const float* base = featT + (size_t)b * HW * CCH + cg + lane;
    for (int pq = wave; pq < 49; pq += 4) {
        const int p = pq / 7;
        const int q = pq - p * 7;
        const int ys = ysA[p], ye = yeA[p];
        const int xs = xsA[q], xe = xeA[q];
        float m = NEGF;
        for (int y = ys; y < ye; ++y) {
            const float* cp = base + ((size_t)y * FW + xs) * CCH;
            for (int x = xs; x < xe; ++x) {
                m = fmaxf(m, *cp);
                cp += CCH;
            }
        }
        smem[pq][lane] = m;
    }
    __syncthreads();

    // phase 2: coalesced flat writes of this block's 64*49 = 3136 outputs
    float* outb = out + (size_t)n * (CCH * 49) + (size_t)cg * 49;
    int flat = tid;                 // local index = c*49 + pq
    int c  = 0, pq = tid;           // tid < 256 -> c = tid/49, pq = tid%49
    c  = tid / 49;
    pq = tid - c * 49;
    #pragma unroll
    for (int k = 0; k < 13; ++k) {
        if (flat < 3136)
            outb[flat] = smem[pq][c];
        flat += 256;
        c += 5; pq += 11;           // 256 = 5*49 + 11
        if (pq >= 49) { pq -= 49; c += 1; }
    }
}

// ---------------- Fallback (ws too small): thread-per-output ----------------
__global__ __launch_bounds__(256) void roipool_fallback(
    const float* __restrict__ feat,
    const float* __restrict__ rois,
    float* __restrict__ out)
{
    int idx = blockIdx.x * blockDim.x + threadIdx.x;
    int q = idx % 7;
    int t = idx / 7;
    int p = t % 7;
    t /= 7;
    int c = t % CCH;
    int n = t / CCH;

    const float* r = rois + n * 5;
    int b  = (int)r[0];
    int x1 = (int)(r[1] * SCALE);
    int y1 = (int)(r[2] * SCALE);
    int x2 = (int)(r[3] * SCALE);
    int y2 = (int)(r[4] * SCALE);
    x1 = min(max(x1, 0), FW - 1);
    y1 = min(max(y1, 0), FH - 1);
    x2 = min(max(x2, 0), FW - 1);
    y2 = min(max(y2, 0), FH - 1);
    int hh = y2 - y1 + 1, ww = x2 - x1 + 1;

    int ys = y1 + (p * hh) / 7, ye = y1 + ((p + 1) * hh + 6) / 7;
    int xs = x1 + (q * ww) / 7, xe = x1 + ((q + 1) * ww + 6) / 7;

    const float* base = feat + ((size_t)b * CCH + c) * HW;
    float m = NEGF;
    for (int y = ys; y < ye; ++y)
        for (int x = xs; x < xe; ++x)
            m = fmaxf(m, base[y * FW + x]);
    out[idx] = m;
}

extern "C" void kernel_launch(void* const* d_in, const int* in_sizes, int n_in,
                              void* d_out, int out_size, void* d_ws, size_t ws_size,
                              hipStream_t stream) {
    const float* feat = (const float*)d_in[0];
    const float* rois = (const float*)d_in[1];
    float* out = (float*)d_out;

    const size_t need = (size_t)4 * HW * CCH * sizeof(float);   // 5.9 MB
    if (ws_size < need) {
        const int total = NROIS * CCH * 49;
        roipool_fallback<<<(total + 255) / 256, 256, 0, stream>>>(feat, rois, out);
        return;
    }

    float* featT = (float*)d_ws;

    dim3 tg((HW + 31) / 32, CCH / 32, 4);   // (46, 8, 4)
    transpose_kernel<<<tg, dim3(32, 8), 0, stream>>>(feat, featT);

    dim3 pg(4, NROIS);                       // 4 channel groups x 512 ROIs
    roipool_kernel<<<pg, 256, 0, stream>>>(featT, rois, out);
}

// Round 5
// 37.622 us; speedup vs baseline: 4.0005x; 1.6135x over previous
//
#include <hip/hip_runtime.h>

// RoI max-pool via channel-last transpose, compile-time-width bin loops.
// features [4,256,38,38] f32, rois [512,5] f32, out [512,256,7,7] f32.

#define NROIS 512
#define CCH   256
#define FH    38
#define FW    38
#define HW    (FH * FW)          // 1444
#define SCALE 0.0625f
#define NEGF  (-3.402823466e+38f)

// ---------------- Kernel 1: transpose [4][256][1444] -> [4][1444][256] ----
// grid (361, 4), block 256. Each block: 4 spatial positions x 256 channels.
// One aligned float4 load per thread (row start 1444*4B = 16B-aligned,
// s0 = 4*blockIdx.x), LDS bounce, 4 coalesced dword stores.
__global__ __launch_bounds__(256) void transpose_kernel(
    const float* __restrict__ src, float* __restrict__ dst)
{
    __shared__ float tile[4][257];
    const int b  = blockIdx.y;
    const int s0 = blockIdx.x * 4;
    const int t  = threadIdx.x;                 // = channel

    const float4 v = *(const float4*)(src + ((size_t)(b * CCH + t)) * HW + s0);
    tile[0][t] = v.x; tile[1][t] = v.y; tile[2][t] = v.z; tile[3][t] = v.w;
    __syncthreads();

    const int s = t >> 6;                       // 0..3
    const int m = t & 63;
    float* drow = dst + ((size_t)b * HW + s0 + s) * CCH;
    #pragma unroll
    for (int k = 0; k < 4; ++k)
        drow[m + 64 * k] = tile[s][m + 64 * k];
}

// ---------------- Kernel 2: pooling ----------------
// grid (4, 512): cg = 64-ch group, n = ROI. 4 waves; wave handles bins
// pq = wave, wave+4, ... All bin math scalar (readfirstlane on wave id).
// Inner loop: switch on bin width W (<=7) -> W unrolled independent loads.

template <int W>
__device__ __forceinline__ float binmax(const float* bp, int h)
{
    float m = NEGF;
    for (int y = 0; y < h; ++y) {
        #pragma unroll
        for (int j = 0; j < W; ++j)
            m = fmaxf(m, bp[j * CCH]);
        bp += FW * CCH;
    }
    return m;
}

__global__ __launch_bounds__(256) void roipool_kernel(
    const float* __restrict__ featT,
    const float* __restrict__ rois,
    float* __restrict__ out)
{
    __shared__ float smem[49][65];

    const int n    = blockIdx.y;
    const int cg   = blockIdx.x * 64;
    const int tid  = threadIdx.x;
    const int wv   = __builtin_amdgcn_readfirstlane(tid >> 6);
    const int lane = tid & 63;

    // ROI decode (uniform per block)
    const float* r = rois + n * 5;
    const int b = (int)r[0];
    int x1 = (int)(r[1] * SCALE);
    int y1 = (int)(r[2] * SCALE);
    int x2 = (int)(r[3] * SCALE);
    int y2 = (int)(r[4] * SCALE);
    x1 = min(max(x1, 0), FW - 1);
    y1 = min(max(y1, 0), FH - 1);
    x2 = min(max(x2, 0), FW - 1);
    y2 = min(max(y2, 0), FH - 1);
    const int hh = y2 - y1 + 1;
    const int ww = x2 - x1 + 1;

    const float* fb = featT + (size_t)b * HW * CCH + cg + lane;

    for (int idx = wv; idx < 49; idx += 4) {
        const int p  = idx / 7;
        const int q  = idx - p * 7;
        const int ys = y1 + (p * hh) / 7;
        const int h  = (y1 + ((p + 1) * hh + 6) / 7) - ys;
        const int xs = x1 + (q * ww) / 7;
        const int W  = (x1 + ((q + 1) * ww + 6) / 7) - xs;

        const float* bp = fb + (size_t)(ys * FW + xs) * CCH;
        float m;
        switch (W) {
            case 1:  m = binmax<1>(bp, h); break;
            case 2:  m = binmax<2>(bp, h); break;
            case 3:  m = binmax<3>(bp, h); break;
            case 4:  m = binmax<4>(bp, h); break;
            case 5:  m = binmax<5>(bp, h); break;
            case 6:  m = binmax<6>(bp, h); break;
            default: m = binmax<7>(bp, h); break;
        }
        smem[idx][lane] = m;
    }
    __syncthreads();

    // coalesced flat writes: 64 ch * 49 bins = 3136 outputs per block
    float* outb = out + (size_t)n * (CCH * 49) + (size_t)cg * 49;
    int flat = tid;
    int c  = tid / 49;
    int pq = tid - c * 49;
    #pragma unroll
    for (int k = 0; k < 13; ++k) {
        if (flat < 3136)
            outb[flat] = smem[pq][c];
        flat += 256;
        c += 5; pq += 11;           // 256 = 5*49 + 11
        if (pq >= 49) { pq -= 49; c += 1; }
    }
}

// ---------------- Fallback (ws too small) ----------------
__global__ __launch_bounds__(256) void roipool_fallback(
    const float* __restrict__ feat,
    const float* __restrict__ rois,
    float* __restrict__ out)
{
    int idx = blockIdx.x * blockDim.x + threadIdx.x;
    int q = idx % 7;
    int t = idx / 7;
    int p = t % 7;
    t /= 7;
    int c = t % CCH;
    int n = t / CCH;

    const float* r = rois + n * 5;
    int b  = (int)r[0];
    int x1 = (int)(r[1] * SCALE);
    int y1 = (int)(r[2] * SCALE);
    int x2 = (int)(r[3] * SCALE);
    int y2 = (int)(r[4] * SCALE);
    x1 = min(max(x1, 0), FW - 1);
    y1 = min(max(y1, 0), FH - 1);
    x2 = min(max(x2, 0), FW - 1);
    y2 = min(max(y2, 0), FH - 1);
    int hh = y2 - y1 + 1, ww = x2 - x1 + 1;

    int ys = y1 + (p * hh) / 7, ye = y1 + ((p + 1) * hh + 6) / 7;
    int xs = x1 + (q * ww) / 7, xe = x1 + ((q + 1) * ww + 6) / 7;

    const float* base = feat + ((size_t)b * CCH + c) * HW;
    float m = NEGF;
    for (int y = ys; y < ye; ++y)
        for (int x = xs; x < xe; ++x)
            m = fmaxf(m, base[y * FW + x]);
    out[idx] = m;
}

extern "C" void kernel_launch(void* const* d_in, const int* in_sizes, int n_in,
                              void* d_out, int out_size, void* d_ws, size_t ws_size,
                              hipStream_t stream) {
    const float* feat = (const float*)d_in[0];
    const float* rois = (const float*)d_in[1];
    float* out = (float*)d_out;

    const size_t need = (size_t)4 * HW * CCH * sizeof(float);   // 5.9 MB
    if (ws_size < need) {
        const int total = NROIS * CCH * 49;
        roipool_fallback<<<(total + 255) / 256, 256, 0, stream>>>(feat, rois, out);
        return;
    }

    float* featT = (float*)d_ws;

    dim3 tg(HW / 4, 4);                      // (361, 4)
    transpose_kernel<<<tg, 256, 0, stream>>>(feat, featT);

    dim3 pg(4, NROIS);                       // 4 channel groups x 512 ROIs
    roipool_kernel<<<pg, 256, 0, stream>>>(featT, rois, out);
}

// Round 6
// 26.828 us; speedup vs baseline: 5.6102x; 1.4024x over previous
//
#include <hip/hip_runtime.h>

// RoI max-pool via channel-last transpose; whole-row compile-time pooling.
// features [4,256,38,38] f32, rois [512,5] f32, out [512,256,7,7] f32.
//
// Kernel 1: transpose features -> featT [4][1444][256] in d_ws.
// Kernel 2: block = (ROI n, 64-ch group), 4 waves; wave w handles p-rows
//           {w, w+4}. switch(ww) -> template<WW>: per y-step, WW independent
//           coalesced loads (lane = channel) + fully-unrolled fmax tree into
//           7 bin accumulators (bin bounds compile-time). Stage in LDS,
//           write out flat/coalesced.

#define NROIS 512
#define CCH   256
#define FH    38
#define FW    38
#define HW    (FH * FW)          // 1444
#define SCALE 0.0625f
#define NEGF  (-3.402823466e+38f)

// ---------------- Kernel 1: transpose [4][256][1444] -> [4][1444][256] ----
__global__ __launch_bounds__(256) void transpose_kernel(
    const float* __restrict__ src, float* __restrict__ dst)
{
    __shared__ float tile[4][257];
    const int b  = blockIdx.y;
    const int s0 = blockIdx.x * 4;
    const int t  = threadIdx.x;                 // = channel

    const float4 v = *(const float4*)(src + ((size_t)(b * CCH + t)) * HW + s0);
    tile[0][t] = v.x; tile[1][t] = v.y; tile[2][t] = v.z; tile[3][t] = v.w;
    __syncthreads();

    const int s = t >> 6;                       // 0..3
    const int m = t & 63;
    float* drow = dst + ((size_t)b * HW + s0 + s) * CCH;
    #pragma unroll
    for (int k = 0; k < 4; ++k)
        drow[m + 64 * k] = tile[s][m + 64 * k];
}

// ---------------- Kernel 2: pooling ----------------
// Whole-ROI pooling for one wave's p-rows, with compile-time row width WW.
template <int WW>
__device__ __forceinline__ void pool_rows(
    const float* __restrict__ fb,   // featT + b*HW*CCH + cg + lane + x1*CCH
    int y1, int hh, int wv, int lane,
    float (*__restrict__ smem)[65])
{
    for (int p = wv; p < 7; p += 4) {
        const int ys = y1 + (p * hh) / 7;
        const int h  = (y1 + ((p + 1) * hh + 6) / 7) - ys;

        float acc[7];
        #pragma unroll
        for (int q = 0; q < 7; ++q) acc[q] = NEGF;

        const float* rb = fb + (size_t)(ys * FW) * CCH;
        for (int y = 0; y < h; ++y) {
            float v[WW];
            #pragma unroll
            for (int j = 0; j < WW; ++j) v[j] = rb[j * CCH];
            #pragma unroll
            for (int q = 0; q < 7; ++q) {
                const int xs = (q * WW) / 7;
                const int xe = ((q + 1) * WW + 6) / 7;
                #pragma unroll
                for (int j = xs; j < xe; ++j)
                    acc[q] = fmaxf(acc[q], v[j]);
            }
            rb += (size_t)FW * CCH;
        }

        #pragma unroll
        for (int q = 0; q < 7; ++q)
            smem[p * 7 + q][lane] = acc[q];
    }
}

__global__ __launch_bounds__(256) void roipool_kernel(
    const float* __restrict__ featT,
    const float* __restrict__ rois,
    float* __restrict__ out)
{
    __shared__ float smem[49][65];

    const int n    = blockIdx.y;
    const int cg   = blockIdx.x * 64;
    const int tid  = threadIdx.x;
    const int wv   = __builtin_amdgcn_readfirstlane(tid >> 6);
    const int lane = tid & 63;

    // ROI decode (uniform per block)
    const float* r = rois + n * 5;
    const int b = (int)r[0];
    int x1 = (int)(r[1] * SCALE);
    int y1 = (int)(r[2] * SCALE);
    int x2 = (int)(r[3] * SCALE);
    int y2 = (int)(r[4] * SCALE);
    x1 = min(max(x1, 0), FW - 1);
    y1 = min(max(y1, 0), FH - 1);
    x2 = min(max(x2, 0), FW - 1);
    y2 = min(max(y2, 0), FH - 1);
    const int hh = y2 - y1 + 1;
    const int ww = x2 - x1 + 1;   // 1..38, uniform for whole block

    const float* fb = featT + (size_t)b * HW * CCH + cg + lane
                    + (size_t)x1 * CCH;

    switch (ww) {
        case  1: pool_rows< 1>(fb, y1, hh, wv, lane, smem); break;
        case  2: pool_rows< 2>(fb, y1, hh, wv, lane, smem); break;
        case  3: pool_rows< 3>(fb, y1, hh, wv, lane, smem); break;
        case  4: pool_rows< 4>(fb, y1, hh, wv, lane, smem); break;
        case  5: pool_rows< 5>(fb, y1, hh, wv, lane, smem); break;
        case  6: pool_rows< 6>(fb, y1, hh, wv, lane, smem); break;
        case  7: pool_rows< 7>(fb, y1, hh, wv, lane, smem); break;
        case  8: pool_rows< 8>(fb, y1, hh, wv, lane, smem); break;
        case  9: pool_rows< 9>(fb, y1, hh, wv, lane, smem); break;
        case 10: pool_rows<10>(fb, y1, hh, wv, lane, smem); break;
        case 11: pool_rows<11>(fb, y1, hh, wv, lane, smem); break;
        case 12: pool_rows<12>(fb, y1, hh, wv, lane, smem); break;
        case 13: pool_rows<13>(fb, y1, hh, wv, lane, smem); break;
        case 14: pool_rows<14>(fb, y1, hh, wv, lane, smem); break;
        case 15: pool_rows<15>(fb, y1, hh, wv, lane, smem); break;
        case 16: pool_rows<16>(fb, y1, hh, wv, lane, smem); break;
        case 17: pool_rows<17>(fb, y1, hh, wv, lane, smem); break;
        case 18: pool_rows<18>(fb, y1, hh, wv, lane, smem); break;
        case 19: pool_rows<19>(fb, y1, hh, wv, lane, smem); break;
        case 20: pool_rows<20>(fb, y1, hh, wv, lane, smem); break;
        case 21: pool_rows<21>(fb, y1, hh, wv, lane, smem); break;
        case 22: pool_rows<22>(fb, y1, hh, wv, lane, smem); break;
        case 23: pool_rows<23>(fb, y1, hh, wv, lane, smem); break;
        case 24: pool_rows<24>(fb, y1, hh, wv, lane, smem); break;
        case 25: pool_rows<25>(fb, y1, hh, wv, lane, smem); break;
        case 26: pool_rows<26>(fb, y1, hh, wv, lane, smem); break;
        case 27: pool_rows<27>(fb, y1, hh, wv, lane, smem); break;
        case 28: pool_rows<28>(fb, y1, hh, wv, lane, smem); break;
        case 29: pool_rows<29>(fb, y1, hh, wv, lane, smem); break;
        case 30: pool_rows<30>(fb, y1, hh, wv, lane, smem); break;
        case 31: pool_rows<31>(fb, y1, hh, wv, lane, smem); break;
        case 32: pool_rows<32>(fb, y1, hh, wv, lane, smem); break;
        case 33: pool_rows<33>(fb, y1, hh, wv, lane, smem); break;
        case 34: pool_rows<34>(fb, y1, hh, wv, lane, smem); break;
        case 35: pool_rows<35>(fb, y1, hh, wv, lane, smem); break;
        case 36: pool_rows<36>(fb, y1, hh, wv, lane, smem); break;
        case 37: pool_rows<37>(fb, y1, hh, wv, lane, smem); break;
        default: pool_rows<38>(fb, y1, hh, wv, lane, smem); break;
    }

    __syncthreads();

    // coalesced flat writes: 64 ch * 49 bins = 3136 outputs per block
    float* outb = out + (size_t)n * (CCH * 49) + (size_t)cg * 49;
    int flat = tid;
    int c  = tid / 49;
    int pq = tid - c * 49;
    #pragma unroll
    for (int k = 0; k < 13; ++k) {
        if (flat < 3136)
            outb[flat] = smem[pq][c];
        flat += 256;
        c += 5; pq += 11;           // 256 = 5*49 + 11
        if (pq >= 49) { pq -= 49; c += 1; }
    }
}

// ---------------- Fallback (ws too small) ----------------
__global__ __launch_bounds__(256) void roipool_fallback(
    const float* __restrict__ feat,
    const float* __restrict__ rois,
    float* __restrict__ out)
{
    int idx = blockIdx.x * blockDim.x + threadIdx.x;
    int q = idx % 7;
    int t = idx / 7;
    int p = t % 7;
    t /= 7;
    int c = t % CCH;
    int n = t / CCH;

    const float* r = rois + n * 5;
    int b  = (int)r[0];
    int x1 = (int)(r[1] * SCALE);
    int y1 = (int)(r[2] * SCALE);
    int x2 = (int)(r[3] * SCALE);
    int y2 = (int)(r[4] * SCALE);
    x1 = min(max(x1, 0), FW - 1);
    y1 = min(max(y1, 0), FH - 1);
    x2 = min(max(x2, 0), FW - 1);
    y2 = min(max(y2, 0), FH - 1);
    int hh = y2 - y1 + 1, ww = x2 - x1 + 1;

    int ys = y1 + (p * hh) / 7, ye = y1 + ((p + 1) * hh + 6) / 7;
    int xs = x1 + (q * ww) / 7, xe = x1 + ((q + 1) * ww + 6) / 7;

    const float* base = feat + ((size_t)b * CCH + c) * HW;
    float m = NEGF;
    for (int y = ys; y < ye; ++y)
        for (int x = xs; x < xe; ++x)
            m = fmaxf(m, base[y * FW + x]);
    out[idx] = m;
}

extern "C" void kernel_launch(void* const* d_in, const int* in_sizes, int n_in,
                              void* d_out, int out_size, void* d_ws, size_t ws_size,
                              hipStream_t stream) {
    const float* feat = (const float*)d_in[0];
    const float* rois = (const float*)d_in[1];
    float* out = (float*)d_out;

    const size_t need = (size_t)4 * HW * CCH * sizeof(float);   // 5.9 MB
    if (ws_size < need) {
        const int total = NROIS * CCH * 49;
        roipool_fallback<<<(total + 255) / 256, 256, 0, stream>>>(feat, rois, out);
        return;
    }

    float* featT = (float*)d_ws;

    dim3 tg(HW / 4, 4);                      // (361, 4)
    transpose_kernel<<<tg, 256, 0, stream>>>(feat, featT);

    dim3 pg(4, NROIS);                       // 4 channel groups x 512 ROIs
    roipool_kernel<<<pg, 256, 0, stream>>>(featT, rois, out);
}